// Round 8
// baseline (405.333 us; speedup 1.0000x reference)
//
#include <hip/hip_runtime.h>
#include <hip/hip_bf16.h>
#include <stdint.h>

typedef __bf16 bf16_t;
typedef bf16_t bf16x8 __attribute__((ext_vector_type(8)));
typedef float f32x4 __attribute__((ext_vector_type(4)));

#define AS1 __attribute__((address_space(1)))
#define AS3 __attribute__((address_space(3)))

__device__ __forceinline__ void gload_lds16(const void* g, void* l) {
    __builtin_amdgcn_global_load_lds((AS1 void*)(g), (AS3 void*)(l), 16, 0, 0);
}

// ---------------- weight cast ----------------
__global__ __launch_bounds__(256) void cast_w_kernel(
    const float* __restrict__ w1, const float* __restrict__ w2,
    bf16_t* __restrict__ w1b, bf16_t* __restrict__ w2b) {
    for (int i = blockIdx.x * 256 + threadIdx.x; i < 262144; i += 32768) {
        if (i < 196608) w1b[i] = (bf16_t)w1[i];
        else            w2b[i - 196608] = (bf16_t)w2[i - 196608];
    }
}

// ---------------- tiled transpose f32 -> bf16 ----------------
// in [b][R][C] f32  ->  out [b][C][out_stride] at column offset out_off
__global__ __launch_bounds__(256) void transpose_cast_kernel(
    const float* __restrict__ in, bf16_t* __restrict__ out,
    int R, int C, int out_stride, int out_off) {
    __shared__ float tile[32][33];
    int b = blockIdx.z;
    const float* inb = in + (size_t)b * R * C;
    bf16_t* outb = out + (size_t)b * C * out_stride;
    int c0 = blockIdx.x * 32, r0 = blockIdx.y * 32;
    int tx = threadIdx.x, ty = threadIdx.y;  // (32,8)
#pragma unroll
    for (int i = 0; i < 4; ++i)
        tile[ty + i * 8][tx] = inb[(size_t)(r0 + ty + i * 8) * C + c0 + tx];
    __syncthreads();
#pragma unroll
    for (int i = 0; i < 4; ++i)
        outb[(size_t)(c0 + ty + i * 8) * out_stride + out_off + r0 + tx] =
            (bf16_t)tile[tx][ty + i * 8];
}

// ---------------- 3-NN: bit-exact f32 mirror of the np reference ----------------
// d2 = (sum(d*d) + sum(s*s)) - 2*dot(d,s), all f32, no FMA contraction,
// top-3 on UNCLAMPED d2, stable lowest-index tie-break, clamp after select.
__device__ __forceinline__ void insert3f(float d, int j,
    float& b0, float& b1, float& b2, int& i0, int& i1, int& i2) {
    if (d < b2) {
        if (d < b1) {
            b2 = b1; i2 = i1;
            if (d < b0) { b1 = b0; i1 = i0; b0 = d; i0 = j; }
            else        { b1 = d;  i1 = j; }
        } else { b2 = d; i2 = j; }
    }
}

__global__ __launch_bounds__(256) void knn_kernel(
    const float* __restrict__ xyz, const float* __restrict__ sub_xyz,
    int* __restrict__ idx_out, float* __restrict__ w_out) {
    const int N = 8192, M = 2048;
    __shared__ float sx[2048], sy[2048], sz[2048], s2[2048];
    int b = blockIdx.y;
    int n0 = blockIdx.x * 64;
    for (int j = threadIdx.x; j < M; j += 256) {
        float vx = sub_xyz[(size_t)(b * 3 + 0) * M + j];
        float vy = sub_xyz[(size_t)(b * 3 + 1) * M + j];
        float vz = sub_xyz[(size_t)(b * 3 + 2) * M + j];
        sx[j] = vx; sy[j] = vy; sz[j] = vz;
        // sum(s*s, -1): ((sx^2 + sy^2) + sz^2), each op rounded f32
        s2[j] = __fadd_rn(__fadd_rn(__fmul_rn(vx, vx), __fmul_rn(vy, vy)),
                          __fmul_rn(vz, vz));
    }
    __syncthreads();
    int p = threadIdx.x >> 2, c = threadIdx.x & 3;
    int n = n0 + p;
    float qx = xyz[(size_t)(b * 3 + 0) * N + n];
    float qy = xyz[(size_t)(b * 3 + 1) * N + n];
    float qz = xyz[(size_t)(b * 3 + 2) * N + n];
    // sum(d*d, -1)
    float t1 = __fadd_rn(__fadd_rn(__fmul_rn(qx, qx), __fmul_rn(qy, qy)),
                         __fmul_rn(qz, qz));
    float b0 = 1e30f, b1 = 1e30f, b2 = 1e30f;
    int i0 = 0, i1 = 0, i2 = 0;
    int jbeg = c * 512;
#pragma unroll 4
    for (int j = jbeg; j < jbeg + 512; ++j) {
        // e = dot(d, s): ((qx*sx + qy*sy) + qz*sz)
        float e = __fadd_rn(__fadd_rn(__fmul_rn(qx, sx[j]), __fmul_rn(qy, sy[j])),
                            __fmul_rn(qz, sz[j]));
        // d2 = (t1 + t2) - 2*e   (2*e is exact)
        float d = __fsub_rn(__fadd_rn(t1, s2[j]), __fmul_rn(2.0f, e));
        insert3f(d, j, b0, b1, b2, i0, i1, i2);
    }
    // merge 4 chunk-lists; strict < keeps lower chunk/index on exact ties
    for (int off = 1; off < 4; off <<= 1) {
        float e0 = __shfl_xor(b0, off), e1 = __shfl_xor(b1, off), e2 = __shfl_xor(b2, off);
        int j0 = __shfl_xor(i0, off), j1 = __shfl_xor(i1, off), j2 = __shfl_xor(i2, off);
        insert3f(e0, j0, b0, b1, b2, i0, i1, i2);
        insert3f(e1, j1, b0, b1, b2, i0, i1, i2);
        insert3f(e2, j2, b0, b1, b2, i0, i1, i2);
    }
    if (c == 0) {
        // dists = max(d2, 0); w = 1/(dists + 1e-8); w /= (w0+w1)+w2  — f32 ops
        float d0 = fmaxf(b0, 0.0f), d1 = fmaxf(b1, 0.0f), d2c = fmaxf(b2, 0.0f);
        float w0 = __fdiv_rn(1.0f, __fadd_rn(d0, 1e-8f));
        float w1 = __fdiv_rn(1.0f, __fadd_rn(d1, 1e-8f));
        float w2 = __fdiv_rn(1.0f, __fadd_rn(d2c, 1e-8f));
        float s = __fadd_rn(__fadd_rn(w0, w1), w2);
        size_t o = ((size_t)b * N + n) * 3;
        idx_out[o] = i0; idx_out[o + 1] = i1; idx_out[o + 2] = i2;
        w_out[o]     = __fdiv_rn(w0, s);
        w_out[o + 1] = __fdiv_rn(w1, s);
        w_out[o + 2] = __fdiv_rn(w2, s);
    }
}

// ---------------- interpolation into h_t[b][n][256..767] ----------------
__global__ __launch_bounds__(256) void interp_kernel(
    const uint32_t* __restrict__ sub_xt,   // [B][2048][512] bf16 viewed as 256 uints/row
    const int* __restrict__ idx3, const float* __restrict__ w3,
    uint32_t* __restrict__ h_t) {          // [B][8192][768] bf16 viewed as 384 uints/row
    const int N = 8192, M = 2048;
    int b = blockIdx.y, n = blockIdx.x, t = threadIdx.x;
    size_t o = ((size_t)b * N + n) * 3;
    int i0 = idx3[o], i1 = idx3[o + 1], i2 = idx3[o + 2];
    float w0 = w3[o], w1 = w3[o + 1], w2 = w3[o + 2];
    const uint32_t* r0 = sub_xt + ((size_t)b * M + i0) * 256;
    const uint32_t* r1 = sub_xt + ((size_t)b * M + i1) * 256;
    const uint32_t* r2 = sub_xt + ((size_t)b * M + i2) * 256;
    uint32_t u0 = r0[t], u1 = r1[t], u2 = r2[t];
    float lo = w0 * __uint_as_float(u0 << 16) + w1 * __uint_as_float(u1 << 16) +
               w2 * __uint_as_float(u2 << 16);
    float hi = w0 * __uint_as_float(u0 & 0xffff0000u) + w1 * __uint_as_float(u1 & 0xffff0000u) +
               w2 * __uint_as_float(u2 & 0xffff0000u);
    union { bf16_t h[2]; uint32_t u; } pk;
    pk.h[0] = (bf16_t)lo; pk.h[1] = (bf16_t)hi;
    h_t[((size_t)b * N + n) * 384 + 128 + t] = pk.u;
}

// ---------------- bf16 MFMA GEMM ----------------
// Ht [B][N][K] row-major, W [M][K] row-major.
// OUT_NM=1: Y[b][n][m] = sum_k Ht*W   (gemm1)
// OUT_NM=0: Y[b][m][n]                (gemm2)
template <int OUT_NM>
__global__ __launch_bounds__(256) void gemm_kernel(
    const bf16_t* __restrict__ Ht, const bf16_t* __restrict__ W,
    float* __restrict__ Y, int N, int M, int K) {
    __shared__ bf16_t lsH[128 * 64];
    __shared__ bf16_t lsW[128 * 64];
    int b = blockIdx.z, n0 = blockIdx.x * 128, m0 = blockIdx.y * 128;
    int tid = threadIdx.x, lane = tid & 63, wid = tid >> 6;
    int wa = (wid >> 1) * 64;  // output-row dim offset within tile
    int wb = (wid & 1) * 64;   // output-col dim offset
    const bf16_t* gH = Ht + ((size_t)b * N + n0) * K;
    const bf16_t* gW = W + (size_t)m0 * K;
    const bf16_t* lsA = OUT_NM ? lsH : lsW;  // A-operand rows (output rows)
    const bf16_t* lsB = OUT_NM ? lsW : lsH;

    f32x4 acc[4][4] = {};
    int srow = tid >> 3;            // staging row within 32-row group
    int scol = (tid & 7) * 8;       // staging col (elements)

    for (int kt = 0; kt < K; kt += 64) {
#pragma unroll
        for (int r = 0; r < 4; ++r) {
            int row = r * 32 + srow;
            gload_lds16(gH + (size_t)row * K + kt + scol, &lsH[(r * 256 + tid) * 8]);
            gload_lds16(gW + (size_t)row * K + kt + scol, &lsW[(r * 256 + tid) * 8]);
        }
        __syncthreads();
#pragma unroll
        for (int k0 = 0; k0 < 64; k0 += 32) {
            bf16x8 fa[4], fb[4];
#pragma unroll
            for (int f = 0; f < 4; ++f) {
                fa[f] = *(const bf16x8*)&lsA[(wa + f * 16 + (lane & 15)) * 64 + k0 + (lane >> 4) * 8];
                fb[f] = *(const bf16x8*)&lsB[(wb + f * 16 + (lane & 15)) * 64 + k0 + (lane >> 4) * 8];
            }
#pragma unroll
            for (int fi = 0; fi < 4; ++fi)
#pragma unroll
                for (int fj = 0; fj < 4; ++fj)
                    acc[fi][fj] = __builtin_amdgcn_mfma_f32_16x16x32_bf16(
                        fa[fi], fb[fj], acc[fi][fj], 0, 0, 0);
        }
        __syncthreads();
    }

#pragma unroll
    for (int fi = 0; fi < 4; ++fi) {
#pragma unroll
        for (int i = 0; i < 4; ++i) {
            int ra = wa + fi * 16 + (lane >> 4) * 4 + i;  // output-row index within tile
#pragma unroll
            for (int fj = 0; fj < 4; ++fj) {
                int cb = wb + fj * 16 + (lane & 15);       // output-col index within tile
                size_t off = OUT_NM
                    ? ((size_t)b * N + n0 + ra) * M + (m0 + cb)
                    : ((size_t)b * M + m0 + ra) * N + (n0 + cb);
                Y[off] = acc[fi][fj][i];
            }
        }
    }
}

// ---------------- BN stats over rows of [32768][256] (y1 layout) ----------------
__global__ __launch_bounds__(256) void bn_stats_rows_kernel(
    const float* __restrict__ Y, float* __restrict__ sum, float* __restrict__ sq) {
    int m = threadIdx.x;
    size_t r0 = (size_t)blockIdx.x * 128;
    float s = 0.f, q = 0.f;
    for (int r = 0; r < 128; ++r) {
        float v = Y[(r0 + r) * 256 + m];
        s += v; q = fmaf(v, v, q);
    }
    atomicAdd(&sum[m], s);
    atomicAdd(&sq[m], q);
}

// ---------------- BN+ReLU on y1 [b][n][256] -> h2 bf16 same layout ----------------
__global__ __launch_bounds__(256) void bn_relu1_kernel(
    const f32x4* __restrict__ Y, uint2* __restrict__ H2,
    const float* __restrict__ sum, const float* __restrict__ sq,
    const float* __restrict__ g, const float* __restrict__ bb) {
    const float inv = 1.0f / 32768.0f;
    for (size_t i = (size_t)blockIdx.x * 256 + threadIdx.x; i < 2097152;
         i += (size_t)gridDim.x * 256) {
        f32x4 v = Y[i];
        int m0 = ((int)i & 63) * 4;
        union { bf16_t h[4]; uint2 u; } pk;
#pragma unroll
        for (int j = 0; j < 4; ++j) {
            int m = m0 + j;
            float mean = sum[m] * inv;
            float var = sq[m] * inv - mean * mean;
            float sc = g[m] / sqrtf(var + 1e-5f);
            float sh = bb[m] - mean * sc;
            float t = fmaxf(v[j] * sc + sh, 0.f);
            pk.h[j] = (bf16_t)t;
        }
        H2[i] = pk.u;
    }
}

// ---------------- BN stats over y2 [4][256][8192] per channel m ----------------
__global__ __launch_bounds__(256) void bn_stats_cols_kernel(
    const float* __restrict__ Y, float* __restrict__ sum, float* __restrict__ sq) {
    int m = blockIdx.x;
    float s = 0.f, q = 0.f;
    for (int b = 0; b < 4; ++b) {
        const float* row = Y + ((size_t)b * 256 + m) * 8192;
        for (int n = threadIdx.x; n < 8192; n += 256) {
            float v = row[n];
            s += v; q = fmaf(v, v, q);
        }
    }
#pragma unroll
    for (int off = 32; off > 0; off >>= 1) {
        s += __shfl_down(s, off, 64);
        q += __shfl_down(q, off, 64);
    }
    __shared__ float rs[4], rq[4];
    int wid = threadIdx.x >> 6, lane = threadIdx.x & 63;
    if (lane == 0) { rs[wid] = s; rq[wid] = q; }
    __syncthreads();
    if (threadIdx.x == 0) {
        sum[m] = rs[0] + rs[1] + rs[2] + rs[3];
        sq[m] = rq[0] + rq[1] + rq[2] + rq[3];
    }
}

// ---------------- BN+ReLU on y2 [4][256][8192] -> out f32 ----------------
__global__ __launch_bounds__(256) void bn_relu2_kernel(
    const f32x4* __restrict__ Y, f32x4* __restrict__ out,
    const float* __restrict__ sum, const float* __restrict__ sq,
    const float* __restrict__ g, const float* __restrict__ bb) {
    const float inv = 1.0f / 32768.0f;
    for (size_t i = (size_t)blockIdx.x * 256 + threadIdx.x; i < 2097152;
         i += (size_t)gridDim.x * 256) {
        f32x4 v = Y[i];
        int m = ((int)(i >> 11)) & 255;  // 2048 vec4 per (b,m) row
        float mean = sum[m] * inv;
        float var = sq[m] * inv - mean * mean;
        float sc = g[m] / sqrtf(var + 1e-5f);
        float sh = bb[m] - mean * sc;
        f32x4 o;
#pragma unroll
        for (int j = 0; j < 4; ++j) o[j] = fmaxf(v[j] * sc + sh, 0.f);
        out[i] = o;
    }
}

extern "C" void kernel_launch(void* const* d_in, const int* in_sizes, int n_in,
                              void* d_out, int out_size, void* d_ws, size_t ws_size,
                              hipStream_t stream) {
    const float* x       = (const float*)d_in[0];  // [4][256][8192]
    const float* xyz     = (const float*)d_in[1];  // [4][3][8192]
    const float* sub_x   = (const float*)d_in[2];  // [4][512][2048]
    const float* sub_xyz = (const float*)d_in[3];  // [4][3][2048]
    const float* w1      = (const float*)d_in[4];  // [256][768]
    const float* g1      = (const float*)d_in[5];
    const float* b1      = (const float*)d_in[6];
    const float* w2      = (const float*)d_in[7];  // [256][256]
    const float* g2      = (const float*)d_in[8];
    const float* b2      = (const float*)d_in[9];
    float* out = (float*)d_out;
    char* ws = (char*)d_ws;

    // Workspace layout (peak ~89.3 MB):
    //   [0,4096)                stats: sum1/sq1/sum2/sq2 (4*256 f32)
    //   [4096,397312)           w1b bf16 [256][768]
    //   [397312,528384)         w2b bf16 [256][256]
    //   [528384,921600)         idx3 int [4][8192][3]
    //   [921600,1314816)        w3 f32 [4][8192][3]
    //   [1314816,9703424)       sub_xt bf16 [4][2048][512]
    //   [9703424,60035072)      h_t bf16 [4][8192][768]
    //     after gemm1, region reused: y2 f32 [4][256][8192] at head,
    //                                 h2 bf16 [4][8192][256] at tail
    //   [60035072,93589504)     y1 f32 [4][8192][256]
    float*  stats  = (float*)ws;
    bf16_t* w1b    = (bf16_t*)(ws + 4096);
    bf16_t* w2b    = (bf16_t*)(ws + 397312);
    int*    idx3   = (int*)(ws + 528384);
    float*  w3     = (float*)(ws + 921600);
    bf16_t* sub_xt = (bf16_t*)(ws + 1314816);
    bf16_t* h_t    = (bf16_t*)(ws + 9703424);
    float*  y2     = (float*)(ws + 9703424);          // overlay on h_t head
    bf16_t* h2     = (bf16_t*)(ws + 43257856);        // overlay on h_t tail
    float*  y1     = (float*)(ws + 60035072);

    hipMemsetAsync(stats, 0, 4096, stream);
    cast_w_kernel<<<128, 256, 0, stream>>>(w1, w2, w1b, w2b);
    // sub_x [512][2048] -> sub_xt [2048][512]
    transpose_cast_kernel<<<dim3(64, 16, 4), dim3(32, 8), 0, stream>>>(
        sub_x, sub_xt, 512, 2048, 512, 0);
    // x [256][8192] -> h_t[..][0:256]
    transpose_cast_kernel<<<dim3(256, 8, 4), dim3(32, 8), 0, stream>>>(
        x, h_t, 256, 8192, 768, 0);
    knn_kernel<<<dim3(128, 4), 256, 0, stream>>>(xyz, sub_xyz, idx3, w3);
    interp_kernel<<<dim3(8192, 4), 256, 0, stream>>>(
        (const uint32_t*)sub_xt, idx3, w3, (uint32_t*)h_t);
    gemm_kernel<1><<<dim3(64, 2, 4), 256, 0, stream>>>(h_t, w1b, y1, 8192, 256, 768);
    bn_stats_rows_kernel<<<256, 256, 0, stream>>>(y1, stats + 0, stats + 256);
    bn_relu1_kernel<<<2048, 256, 0, stream>>>(
        (const f32x4*)y1, (uint2*)h2, stats + 0, stats + 256, g1, b1);
    gemm_kernel<0><<<dim3(64, 2, 4), 256, 0, stream>>>(h2, w2b, y2, 8192, 256, 256);
    bn_stats_cols_kernel<<<256, 256, 0, stream>>>(y2, stats + 512, stats + 768);
    bn_relu2_kernel<<<2048, 256, 0, stream>>>(
        (const f32x4*)y2, (f32x4*)out, stats + 512, stats + 768, g2, b2);
}